// Round 7
// baseline (595.849 us; speedup 1.0000x reference)
//
#include <hip/hip_runtime.h>
#include <hip/hip_fp16.h>
#include <stdint.h>

// ---------------------------------------------------------------------------
// GraphConv (planetoid-gcn-residual):
//   h   = norm * (x @ W.T + bias),  norm = rsqrt(1+deg)
//   out = norm * (spmm_add(adj,h) + h)
// R7 (570.8 -> 548.8): LDS counting-sort B3, packed 4B edges, nt out stores.
//   Top-5 still saturated by agg (111us x2); ~327us remains INVISIBLE.
// R8: visibility round.
//   - agg: feature-split (2x) -> row-split (8x ~26us). Removes csr+residual
//     re-read redundancy (-16MB) and pushes the top-5 cutoff to ~26us so
//     gemm/scatter/finalize/count surface with real counters.
//   - buckets 256 rows (nbuck=391): csr_finalize was 196 blocks (0.77/CU,
//     under-occupied); 391 blocks + tid-direct 256-bin hist/scan.
// R9: identical resubmit of R8 (container failure, no counters returned).
// ---------------------------------------------------------------------------

#define THREADS 256
#define NB 512             // padded bucket array size (nbuck = 391)
#define B3_EDGES 8192

typedef _Float16 half8 __attribute__((ext_vector_type(8)));
typedef float floatx4 __attribute__((ext_vector_type(4)));

// ---------------- B1: bucket histogram (LDS) + bulk global merge ----------------
__global__ __launch_bounds__(THREADS) void bucket_count(
    const int* __restrict__ rows, int* __restrict__ bcnt, int E, int nbuck) {
    __shared__ int h[NB];
    h[threadIdx.x] = 0; h[threadIdx.x + 256] = 0;
    __syncthreads();
    int nquad  = E >> 2;
    int stride = gridDim.x * THREADS;
    for (int q = blockIdx.x * THREADS + threadIdx.x; q < nquad; q += stride) {
        int4 r = ((const int4*)rows)[q];
        atomicAdd(&h[r.x >> 8], 1);
        atomicAdd(&h[r.y >> 8], 1);
        atomicAdd(&h[r.z >> 8], 1);
        atomicAdd(&h[r.w >> 8], 1);
    }
    if (blockIdx.x == 0)
        for (int e = (nquad << 2) + threadIdx.x; e < E; e += THREADS)
            atomicAdd(&h[rows[e] >> 8], 1);
    __syncthreads();
    for (int b = threadIdx.x; b < nbuck; b += THREADS) {
        int v = h[b];
        if (v) atomicAdd(&bcnt[b], v);
    }
}

// ---------------- B2: exclusive scan over bucket counts (1 block, pair scan) ----------------
__global__ __launch_bounds__(THREADS) void bucket_scan(
    const int* __restrict__ bcnt, int* __restrict__ boff, int* __restrict__ bcur,
    int nbuck, int E) {
    __shared__ int s1[THREADS];
    int tid = threadIdx.x;
    int b0 = 2 * tid, b1 = 2 * tid + 1;
    int v0 = (b0 < nbuck) ? bcnt[b0] : 0;
    int v1 = (b1 < nbuck) ? bcnt[b1] : 0;
    s1[tid] = v0 + v1;
    __syncthreads();
    for (int off = 1; off < THREADS; off <<= 1) {
        int t = (tid >= off) ? s1[tid - off] : 0;
        __syncthreads();
        s1[tid] += t;
        __syncthreads();
    }
    int excl = s1[tid] - (v0 + v1);
    if (b0 < nbuck) { boff[b0] = excl;      bcur[b0] = excl; }
    if (b1 < nbuck) { boff[b1] = excl + v0; bcur[b1] = excl + v0; }
    if (tid == 0) boff[nbuck] = E;
}

// ---------------- B3: LDS counting-sort into bucket-grouped packed buf ----------------
// 8K edges/block staged bucket-ordered in LDS, flushed coalesced per bucket.
__global__ __launch_bounds__(THREADS) void bucket_scatter(
    const int* __restrict__ rows, const int* __restrict__ cols,
    int* __restrict__ bcur, uint32_t* __restrict__ buf, int E, int nbuck) {
    __shared__ uint32_t staged[B3_EDGES];   // 32 KB
    __shared__ int h[NB], lo[NB], gb[NB], hc[NB], s1[THREADS];
    int tid = threadIdx.x;
    h[tid] = 0; h[tid + 256] = 0;
    __syncthreads();
    int e0 = blockIdx.x * B3_EDGES;
    int e1 = e0 + B3_EDGES; if (e1 > E) e1 = E;
    // phase 1: local bucket histogram
    for (int e = e0 + tid; e < e1; e += THREADS)
        atomicAdd(&h[rows[e] >> 8], 1);
    __syncthreads();
    // phase 2: LDS pair-scan over NB buckets + global reservation
    int a0 = h[2 * tid], a1 = h[2 * tid + 1];
    s1[tid] = a0 + a1;
    __syncthreads();
    for (int off = 1; off < THREADS; off <<= 1) {
        int t = (tid >= off) ? s1[tid - off] : 0;
        __syncthreads();
        s1[tid] += t;
        __syncthreads();
    }
    int eps = s1[tid] - (a0 + a1);
    lo[2 * tid]     = eps;
    lo[2 * tid + 1] = eps + a0;
    for (int b = tid; b < NB; b += THREADS) {
        int v = h[b];
        gb[b] = (b < nbuck && v) ? atomicAdd(&bcur[b], v) : 0;
        hc[b] = 0;
    }
    __syncthreads();
    // phase 3: place edges bucket-ordered into LDS (packed 4B: rl<<17 | c)
    for (int e = e0 + tid; e < e1; e += THREADS) {
        int r = rows[e];
        int c = cols[e];
        int b = r >> 8;
        int p = lo[b] + atomicAdd(&hc[b], 1);
        staged[p] = ((uint32_t)(r & 255) << 17) | (uint32_t)c;
    }
    __syncthreads();
    // phase 4: coalesced flush, one wave per bucket round-robin
    int wid = tid >> 6, lane = tid & 63;
    for (int b = wid; b < nbuck; b += 4) {
        int cnt = h[b], src = lo[b], dst = gb[b];
        for (int i = lane; i < cnt; i += 64)
            buf[dst + i] = staged[src + i];
    }
}

// ---------------- B5: per-bucket CSR finalize + rs (block owns 256 rows) ----------------
__global__ __launch_bounds__(THREADS) void csr_finalize(
    const uint32_t* __restrict__ buf, const int* __restrict__ boff,
    int* __restrict__ rs, int* __restrict__ csr, int n, int E) {
    int b   = blockIdx.x;
    int tid = threadIdx.x;
    __shared__ int h[256], base[256], s1[THREADS];
    h[tid] = 0;
    __syncthreads();
    int s = boff[b], e = boff[b + 1];
    for (int i = s + tid; i < e; i += THREADS)
        atomicAdd(&h[buf[i] >> 17], 1);
    __syncthreads();
    int v = h[tid];
    s1[tid] = v;
    __syncthreads();
    for (int off = 1; off < THREADS; off <<= 1) {
        int t = (tid >= off) ? s1[tid - off] : 0;
        __syncthreads();
        s1[tid] += t;
        __syncthreads();
    }
    int myBase = s + s1[tid] - v;
    base[tid] = myBase;
    int row = (b << 8) + tid;
    if (row < n) rs[row] = myBase;
    h[tid] = 0;                           // reuse as cursor
    if (b == 0 && tid == 0) rs[n] = E;
    __syncthreads();
    for (int i = s + tid; i < e; i += THREADS) {
        uint32_t p = buf[i];
        int rl = p >> 17;
        int c  = p & 0x1FFFF;
        int q  = base[rl] + atomicAdd(&h[rl], 1);
        csr[q] = c;
    }
}

// ---------------- W -> f16 B-fragment swizzle ----------------
__global__ void make_bswz(const float* __restrict__ W, half8* __restrict__ Bswz) {
    int t = blockIdx.x * THREADS + threadIdx.x;   // 8192 entries
    int n_tile = t >> 9;
    int k_step = (t >> 6) & 7;
    int lane   = t & 63;
    int q = lane >> 4, m16 = lane & 15;
    const float* src = W + (size_t)(n_tile * 16 + m16) * 256 + k_step * 32 + q * 8;
    half8 h;
#pragma unroll
    for (int j = 0; j < 8; j++) h[j] = (_Float16)src[j];
    Bswz[t] = h;
}

// LDS byte-address swizzle: spread k_step (bits 10-12) and q-parity (bit 8)
// into bits 4-7 so staging writes hit all banks (was ~32-way conflict).
__device__ __forceinline__ int As_swz(int b) {
    return b ^ ((((b >> 10) & 7) ^ (((b >> 8) & 1) << 3)) << 4);
}

// ---------------- f16 MFMA GEMM + bias + norm scale ----------------
// Block: 256 thr = 4 waves. Tile: 64 rows x 256 cols; wave w -> cols [64w,64w+64).
__global__ __launch_bounds__(THREADS) void gemm_mfma(
    const float* __restrict__ x, const half8* __restrict__ Bswz,
    const float* __restrict__ bias, const int* __restrict__ rs,
    _Float16* __restrict__ h16, int n) {
    __shared__ _Float16 As[4 * 8 * 64 * 8];   // 32 KB, A-frag layout (swizzled)
    int tid  = threadIdx.x;
    int row0 = blockIdx.x * 64;

    // stage x tile fp32 -> f16 into (swizzled) A-frag layout
#pragma unroll
    for (int i = 0; i < 16; i++) {
        int flat = i * THREADS + tid;
        int r  = flat >> 6;         // 0..63 row in tile
        int k  = (flat & 63) * 4;   // 0..252 step 4
        float4 v;
        if (row0 + r < n) v = *(const float4*)(x + (size_t)(row0 + r) * 256 + k);
        else { v.x = 0.f; v.y = 0.f; v.z = 0.f; v.w = 0.f; }
        int m_sub  = r >> 4;
        int k_step = k >> 5;
        int q      = (k >> 3) & 3;
        int j      = k & 7;         // 0 or 4
        int lane_w = (r & 15) + (q << 4);
        int entry  = (m_sub * 8 + k_step) * 64 + lane_w;
        union { _Float16 h[4]; uint2 u; } pk;
        pk.h[0] = (_Float16)v.x; pk.h[1] = (_Float16)v.y;
        pk.h[2] = (_Float16)v.z; pk.h[3] = (_Float16)v.w;
        *(uint2*)((char*)As + As_swz(entry * 16 + (j << 1))) = pk.u;
    }
    __syncthreads();

    int w    = tid >> 6;    // wave id = n-slice
    int lane = tid & 63;

    floatx4 acc[4][4];
#pragma unroll
    for (int ms = 0; ms < 4; ms++)
#pragma unroll
        for (int nn = 0; nn < 4; nn++) {
            acc[ms][nn][0] = 0.f; acc[ms][nn][1] = 0.f;
            acc[ms][nn][2] = 0.f; acc[ms][nn][3] = 0.f;
        }

    for (int ks = 0; ks < 8; ks++) {
        half8 bfrag[4];
#pragma unroll
        for (int nn = 0; nn < 4; nn++)
            bfrag[nn] = Bswz[((w * 4 + nn) * 8 + ks) * 64 + lane];
        half8 afrag[4];
#pragma unroll
        for (int ms = 0; ms < 4; ms++)
            afrag[ms] = *(const half8*)((char*)As +
                            As_swz(((ms * 8 + ks) * 64 + lane) * 16));
#pragma unroll
        for (int ms = 0; ms < 4; ms++)
#pragma unroll
            for (int nn = 0; nn < 4; nn++)
                acc[ms][nn] = __builtin_amdgcn_mfma_f32_16x16x32_f16(
                    afrag[ms], bfrag[nn], acc[ms][nn], 0, 0, 0);
    }

    // epilogue: C/D layout col=lane&15, row=(lane>>4)*4+i
    int rgrp = lane >> 4;
    int cl   = lane & 15;
#pragma unroll
    for (int ms = 0; ms < 4; ms++) {
        int rbase = row0 + ms * 16 + rgrp * 4;
        float nrm[4];
#pragma unroll
        for (int i = 0; i < 4; i++) {
            int r = rbase + i;
            nrm[i] = (r < n) ? rsqrtf(1.0f + (float)(rs[r + 1] - rs[r])) : 0.f;
        }
#pragma unroll
        for (int nn = 0; nn < 4; nn++) {
            int col = w * 64 + nn * 16 + cl;
            float bb = bias[col];
#pragma unroll
            for (int i = 0; i < 4; i++) {
                int r = rbase + i;
                if (r < n)
                    h16[(size_t)r * 256 + col] =
                        (_Float16)((acc[ms][nn][i] + bb) * nrm[i]);
            }
        }
    }
}

// ---------------- aggregation over a row range (full 256 cols) ----------------
// Wave per row, half-wave (32 lanes x 16B) per edge, 2 edges in flight.
__global__ __launch_bounds__(THREADS) void agg_rows(
    const _Float16* __restrict__ h16, const int* __restrict__ csr_col,
    const int* __restrict__ rs, float* __restrict__ out, int r0, int r1) {
    int row = r0 + blockIdx.x * 4 + (threadIdx.x >> 6);
    if (row >= r1) return;
    int lane = threadIdx.x & 63;
    int half = lane >> 5;
    int l32  = lane & 31;
    int off  = l32 * 8;   // 8 f16 cols per lane, 32 lanes cover the row

    int s   = rs[row];
    int end = rs[row + 1];

    float acc[8] = {0.f, 0.f, 0.f, 0.f, 0.f, 0.f, 0.f, 0.f};
    if (half == 0) {   // residual h_scaled[row]
        half8 v = *(const half8*)(h16 + (size_t)row * 256 + off);
#pragma unroll
        for (int j = 0; j < 8; j++) acc[j] = (float)v[j];
    }

    int e = s + half;   // half 0 takes even-offset edges, half 1 odd
    for (; e + 2 < end; e += 4) {
        int c0 = csr_col[e];
        int c1 = csr_col[e + 2];
        half8 v0 = *(const half8*)(h16 + (size_t)c0 * 256 + off);
        half8 v1 = *(const half8*)(h16 + (size_t)c1 * 256 + off);
#pragma unroll
        for (int j = 0; j < 8; j++) acc[j] += (float)v0[j] + (float)v1[j];
    }
    for (; e < end; e += 2) {
        int c = csr_col[e];
        half8 v = *(const half8*)(h16 + (size_t)c * 256 + off);
#pragma unroll
        for (int j = 0; j < 8; j++) acc[j] += (float)v[j];
    }

    // cross-half reduction: lane L += lane L+32
#pragma unroll
    for (int j = 0; j < 8; j++) acc[j] += __shfl_down(acc[j], 32);

    if (half == 0) {
        float nrm = rsqrtf(1.0f + (float)(end - s));
        floatx4 o0, o1;
        o0[0] = acc[0] * nrm; o0[1] = acc[1] * nrm; o0[2] = acc[2] * nrm; o0[3] = acc[3] * nrm;
        o1[0] = acc[4] * nrm; o1[1] = acc[5] * nrm; o1[2] = acc[6] * nrm; o1[3] = acc[7] * nrm;
        float* dst = out + (size_t)row * 256 + off;
        __builtin_nontemporal_store(o0, (floatx4*)dst);
        __builtin_nontemporal_store(o1, (floatx4*)(dst + 4));
    }
}

// ---------------------------------------------------------------------------
extern "C" void kernel_launch(void* const* d_in, const int* in_sizes, int n_in,
                              void* d_out, int out_size, void* d_ws, size_t ws_size,
                              hipStream_t stream) {
    const float* x    = (const float*)d_in[0];
    const float* W    = (const float*)d_in[1];
    const float* bias = (const float*)d_in[2];
    const int*   rows = (const int*)d_in[3];
    const int*   cols = (const int*)d_in[4];

    const int D = 256;
    int n = in_sizes[0] / D;    // 100000
    int E = in_sizes[3];        // 3200000
    int nbuck = (n + 255) >> 8; // 391 (<= NB)

    // ---- workspace carve ----
    char* p = (char*)d_ws;
    auto alignup = [](size_t v) { return (v + 255) & ~(size_t)255; };
    _Float16* h16 = (_Float16*)p; p += alignup((size_t)n * D * sizeof(_Float16)); // 51.2 MB
    int*   rs     = (int*)p;    p += alignup((size_t)(n + 1) * sizeof(int));
    int*   csr    = (int*)p;    p += alignup((size_t)E * sizeof(int));            // 12.8 MB
    half8* Bswz   = (half8*)p;  p += alignup((size_t)8192 * sizeof(half8));       // 128 KB
    int*   bcnt   = (int*)p;    p += alignup((size_t)NB * sizeof(int));
    int*   boff   = (int*)p;    p += alignup((size_t)(NB + 1) * sizeof(int));
    int*   bcur   = (int*)p;    p += alignup((size_t)NB * sizeof(int));

    // buf[] (packed 4B per edge, 12.8 MB) overlays the h16 region (51.2 MB);
    // h16 is written by gemm only AFTER csr_finalize has consumed buf.
    uint32_t* buf = (uint32_t*)h16;

    hipMemsetAsync(bcnt, 0, (size_t)nbuck * sizeof(int), stream);

    bucket_count<<<256, THREADS, 0, stream>>>(rows, bcnt, E, nbuck);
    bucket_scan<<<1, THREADS, 0, stream>>>(bcnt, boff, bcur, nbuck, E);

    int b3blocks = (E + B3_EDGES - 1) / B3_EDGES;   // 391
    bucket_scatter<<<b3blocks, THREADS, 0, stream>>>(rows, cols, bcur, buf, E, nbuck);

    csr_finalize<<<nbuck, THREADS, 0, stream>>>(buf, boff, rs, csr, n, E);

    make_bswz<<<32, THREADS, 0, stream>>>(W, Bswz);

    int gblocks = (n + 63) / 64;   // 1563
    gemm_mfma<<<gblocks, THREADS, 0, stream>>>(x, Bswz, bias, rs, h16, n);

    // agg: 8 row-range dispatches (visibility: pushes top-5 cutoff to ~26us)
    int chunk = (n + 7) / 8;       // 12500
    for (int d = 0; d < 8; ++d) {
        int a0 = d * chunk;
        int a1 = a0 + chunk; if (a1 > n) a1 = n;
        if (a0 >= a1) break;
        int ablocks = (a1 - a0 + 3) / 4;
        agg_rows<<<ablocks, THREADS, 0, stream>>>(h16, csr, rs, (float*)d_out, a0, a1);
    }
}

// Round 8
// 548.150 us; speedup vs baseline: 1.0870x; 1.0870x over previous
//
#include <hip/hip_runtime.h>
#include <hip/hip_fp16.h>
#include <stdint.h>

// ---------------------------------------------------------------------------
// GraphConv (planetoid-gcn-residual):
//   h   = norm * (x @ W.T + bias),  norm = rsqrt(1+deg)
//   out = norm * (spmm_add(adj,h) + h)
// R8 (595.8, visibility): gemm_mfma exposed as #1 (88.5us, MfmaUtil 5.5%,
//   occupancy 24.8%, 2.0M LDS bank conflicts, VGPR only 72 -> no pipelining).
//   8-way agg split cost ~47us of launch gaps.
// R10:
//   - gemm staging: one thread -> one full 16B A-frag entry (2x float4 ->
//     pack 8 f16 -> single b128 write). Linear per-wave LDS addresses;
//     conflict-free by construction; As_swz swizzle DELETED.
//   - gemm ks loop: explicit depth-1 software pipeline (bf/af[2][4], fully
//     unrolled, static indices) so B-loads for ks+1 overlap MFMAs of ks.
//   - agg: row-split x2 dispatches (keeps -16MB vs feature-split, drops 6
//     launch gaps, keeps gemm visible in top-5).
// ---------------------------------------------------------------------------

#define THREADS 256
#define NB 512             // padded bucket array size (nbuck = 391)
#define B3_EDGES 8192

typedef _Float16 half8 __attribute__((ext_vector_type(8)));
typedef float floatx4 __attribute__((ext_vector_type(4)));

// ---------------- B1: bucket histogram (LDS) + bulk global merge ----------------
__global__ __launch_bounds__(THREADS) void bucket_count(
    const int* __restrict__ rows, int* __restrict__ bcnt, int E, int nbuck) {
    __shared__ int h[NB];
    h[threadIdx.x] = 0; h[threadIdx.x + 256] = 0;
    __syncthreads();
    int nquad  = E >> 2;
    int stride = gridDim.x * THREADS;
    for (int q = blockIdx.x * THREADS + threadIdx.x; q < nquad; q += stride) {
        int4 r = ((const int4*)rows)[q];
        atomicAdd(&h[r.x >> 8], 1);
        atomicAdd(&h[r.y >> 8], 1);
        atomicAdd(&h[r.z >> 8], 1);
        atomicAdd(&h[r.w >> 8], 1);
    }
    if (blockIdx.x == 0)
        for (int e = (nquad << 2) + threadIdx.x; e < E; e += THREADS)
            atomicAdd(&h[rows[e] >> 8], 1);
    __syncthreads();
    for (int b = threadIdx.x; b < nbuck; b += THREADS) {
        int v = h[b];
        if (v) atomicAdd(&bcnt[b], v);
    }
}

// ---------------- B2: exclusive scan over bucket counts (1 block, pair scan) ----------------
__global__ __launch_bounds__(THREADS) void bucket_scan(
    const int* __restrict__ bcnt, int* __restrict__ boff, int* __restrict__ bcur,
    int nbuck, int E) {
    __shared__ int s1[THREADS];
    int tid = threadIdx.x;
    int b0 = 2 * tid, b1 = 2 * tid + 1;
    int v0 = (b0 < nbuck) ? bcnt[b0] : 0;
    int v1 = (b1 < nbuck) ? bcnt[b1] : 0;
    s1[tid] = v0 + v1;
    __syncthreads();
    for (int off = 1; off < THREADS; off <<= 1) {
        int t = (tid >= off) ? s1[tid - off] : 0;
        __syncthreads();
        s1[tid] += t;
        __syncthreads();
    }
    int excl = s1[tid] - (v0 + v1);
    if (b0 < nbuck) { boff[b0] = excl;      bcur[b0] = excl; }
    if (b1 < nbuck) { boff[b1] = excl + v0; bcur[b1] = excl + v0; }
    if (tid == 0) boff[nbuck] = E;
}

// ---------------- B3: LDS counting-sort into bucket-grouped packed buf ----------------
__global__ __launch_bounds__(THREADS) void bucket_scatter(
    const int* __restrict__ rows, const int* __restrict__ cols,
    int* __restrict__ bcur, uint32_t* __restrict__ buf, int E, int nbuck) {
    __shared__ uint32_t staged[B3_EDGES];   // 32 KB
    __shared__ int h[NB], lo[NB], gb[NB], hc[NB], s1[THREADS];
    int tid = threadIdx.x;
    h[tid] = 0; h[tid + 256] = 0;
    __syncthreads();
    int e0 = blockIdx.x * B3_EDGES;
    int e1 = e0 + B3_EDGES; if (e1 > E) e1 = E;
    // phase 1: local bucket histogram
    for (int e = e0 + tid; e < e1; e += THREADS)
        atomicAdd(&h[rows[e] >> 8], 1);
    __syncthreads();
    // phase 2: LDS pair-scan over NB buckets + global reservation
    int a0 = h[2 * tid], a1 = h[2 * tid + 1];
    s1[tid] = a0 + a1;
    __syncthreads();
    for (int off = 1; off < THREADS; off <<= 1) {
        int t = (tid >= off) ? s1[tid - off] : 0;
        __syncthreads();
        s1[tid] += t;
        __syncthreads();
    }
    int eps = s1[tid] - (a0 + a1);
    lo[2 * tid]     = eps;
    lo[2 * tid + 1] = eps + a0;
    for (int b = tid; b < NB; b += THREADS) {
        int v = h[b];
        gb[b] = (b < nbuck && v) ? atomicAdd(&bcur[b], v) : 0;
        hc[b] = 0;
    }
    __syncthreads();
    // phase 3: place edges bucket-ordered into LDS (packed 4B: rl<<17 | c)
    for (int e = e0 + tid; e < e1; e += THREADS) {
        int r = rows[e];
        int c = cols[e];
        int b = r >> 8;
        int p = lo[b] + atomicAdd(&hc[b], 1);
        staged[p] = ((uint32_t)(r & 255) << 17) | (uint32_t)c;
    }
    __syncthreads();
    // phase 4: coalesced flush, one wave per bucket round-robin
    int wid = tid >> 6, lane = tid & 63;
    for (int b = wid; b < nbuck; b += 4) {
        int cnt = h[b], src = lo[b], dst = gb[b];
        for (int i = lane; i < cnt; i += 64)
            buf[dst + i] = staged[src + i];
    }
}

// ---------------- B5: per-bucket CSR finalize + rs (block owns 256 rows) ----------------
__global__ __launch_bounds__(THREADS) void csr_finalize(
    const uint32_t* __restrict__ buf, const int* __restrict__ boff,
    int* __restrict__ rs, int* __restrict__ csr, int n, int E) {
    int b   = blockIdx.x;
    int tid = threadIdx.x;
    __shared__ int h[256], base[256], s1[THREADS];
    h[tid] = 0;
    __syncthreads();
    int s = boff[b], e = boff[b + 1];
    for (int i = s + tid; i < e; i += THREADS)
        atomicAdd(&h[buf[i] >> 17], 1);
    __syncthreads();
    int v = h[tid];
    s1[tid] = v;
    __syncthreads();
    for (int off = 1; off < THREADS; off <<= 1) {
        int t = (tid >= off) ? s1[tid - off] : 0;
        __syncthreads();
        s1[tid] += t;
        __syncthreads();
    }
    int myBase = s + s1[tid] - v;
    base[tid] = myBase;
    int row = (b << 8) + tid;
    if (row < n) rs[row] = myBase;
    h[tid] = 0;                           // reuse as cursor
    if (b == 0 && tid == 0) rs[n] = E;
    __syncthreads();
    for (int i = s + tid; i < e; i += THREADS) {
        uint32_t p = buf[i];
        int rl = p >> 17;
        int c  = p & 0x1FFFF;
        int q  = base[rl] + atomicAdd(&h[rl], 1);
        csr[q] = c;
    }
}

// ---------------- W -> f16 B-fragment swizzle ----------------
__global__ void make_bswz(const float* __restrict__ W, half8* __restrict__ Bswz) {
    int t = blockIdx.x * THREADS + threadIdx.x;   // 8192 entries
    int n_tile = t >> 9;
    int k_step = (t >> 6) & 7;
    int lane   = t & 63;
    int q = lane >> 4, m16 = lane & 15;
    const float* src = W + (size_t)(n_tile * 16 + m16) * 256 + k_step * 32 + q * 8;
    half8 h;
#pragma unroll
    for (int j = 0; j < 8; j++) h[j] = (_Float16)src[j];
    Bswz[t] = h;
}

// ---------------- f16 MFMA GEMM + bias + norm scale ----------------
// Block: 256 thr = 4 waves. Tile: 64 rows x 256 cols; wave w -> cols [64w,64w+64).
// R10: staging = 1 thread -> 1 full b128 A-frag entry (conflict-free, no
// swizzle); ks loop depth-1 software-pipelined.
__global__ __launch_bounds__(THREADS) void gemm_mfma(
    const float* __restrict__ x, const half8* __restrict__ Bswz,
    const float* __restrict__ bias, const int* __restrict__ rs,
    _Float16* __restrict__ h16, int n) {
    __shared__ _Float16 As[4 * 8 * 64 * 8];   // 32 KB, A-frag layout (linear)
    int tid  = threadIdx.x;
    int row0 = blockIdx.x * 64;

    // stage x tile fp32 -> f16: thread owns one 16B entry = one b128 write.
    // entry = (m_sub*8 + k_step)*64 + lane_w, lane_w = (r&15) + (q<<4),
    // holds x[row0 + m_sub*16 + (r&15)][k_step*32 + q*8 + 0..7].
#pragma unroll
    for (int i = 0; i < 8; i++) {
        int entry  = i * 256 + tid;         // 0..2047
        int m_sub  = entry >> 9;
        int k_step = (entry >> 6) & 7;
        int lw     = entry & 63;
        int r      = m_sub * 16 + (lw & 15);
        int k      = k_step * 32 + (lw >> 4) * 8;
        float4 v0, v1;
        if (row0 + r < n) {
            const float* src = x + (size_t)(row0 + r) * 256 + k;
            v0 = *(const float4*)src;
            v1 = *(const float4*)(src + 4);
        } else {
            v0.x = v0.y = v0.z = v0.w = 0.f;
            v1.x = v1.y = v1.z = v1.w = 0.f;
        }
        union { _Float16 h[8]; uint4 u; } pk;
        pk.h[0] = (_Float16)v0.x; pk.h[1] = (_Float16)v0.y;
        pk.h[2] = (_Float16)v0.z; pk.h[3] = (_Float16)v0.w;
        pk.h[4] = (_Float16)v1.x; pk.h[5] = (_Float16)v1.y;
        pk.h[6] = (_Float16)v1.z; pk.h[7] = (_Float16)v1.w;
        *(uint4*)(As + entry * 8) = pk.u;
    }
    __syncthreads();

    int w    = tid >> 6;    // wave id = n-slice
    int lane = tid & 63;

    floatx4 acc[4][4];
#pragma unroll
    for (int ms = 0; ms < 4; ms++)
#pragma unroll
        for (int nn = 0; nn < 4; nn++) {
            acc[ms][nn][0] = 0.f; acc[ms][nn][1] = 0.f;
            acc[ms][nn][2] = 0.f; acc[ms][nn][3] = 0.f;
        }

    // depth-1 software pipeline: loads for ks+1 issue before MFMAs of ks.
    half8 bf[2][4], af[2][4];
#pragma unroll
    for (int nn = 0; nn < 4; nn++)
        bf[0][nn] = Bswz[((w * 4 + nn) * 8 + 0) * 64 + lane];
#pragma unroll
    for (int ms = 0; ms < 4; ms++)
        af[0][ms] = *(const half8*)(As + ((ms * 8 + 0) * 64 + lane) * 8);

#pragma unroll
    for (int ks = 0; ks < 8; ks++) {
        int cur = ks & 1, nxt = cur ^ 1;    // static after full unroll
        if (ks < 7) {
#pragma unroll
            for (int nn = 0; nn < 4; nn++)
                bf[nxt][nn] = Bswz[((w * 4 + nn) * 8 + ks + 1) * 64 + lane];
#pragma unroll
            for (int ms = 0; ms < 4; ms++)
                af[nxt][ms] = *(const half8*)(As + ((ms * 8 + ks + 1) * 64 + lane) * 8);
        }
#pragma unroll
        for (int ms = 0; ms < 4; ms++)
#pragma unroll
            for (int nn = 0; nn < 4; nn++)
                acc[ms][nn] = __builtin_amdgcn_mfma_f32_16x16x32_f16(
                    af[cur][ms], bf[cur][nn], acc[ms][nn], 0, 0, 0);
    }

    // epilogue: C/D layout col=lane&15, row=(lane>>4)*4+i
    int rgrp = lane >> 4;
    int cl   = lane & 15;
#pragma unroll
    for (int ms = 0; ms < 4; ms++) {
        int rbase = row0 + ms * 16 + rgrp * 4;
        float nrm[4];
#pragma unroll
        for (int i = 0; i < 4; i++) {
            int r = rbase + i;
            nrm[i] = (r < n) ? rsqrtf(1.0f + (float)(rs[r + 1] - rs[r])) : 0.f;
        }
#pragma unroll
        for (int nn = 0; nn < 4; nn++) {
            int col = w * 64 + nn * 16 + cl;
            float bb = bias[col];
#pragma unroll
            for (int i = 0; i < 4; i++) {
                int r = rbase + i;
                if (r < n)
                    h16[(size_t)r * 256 + col] =
                        (_Float16)((acc[ms][nn][i] + bb) * nrm[i]);
            }
        }
    }
}

// ---------------- aggregation over a row range (full 256 cols) ----------------
// Wave per row, half-wave (32 lanes x 16B) per edge, 2 edges in flight.
__global__ __launch_bounds__(THREADS) void agg_rows(
    const _Float16* __restrict__ h16, const int* __restrict__ csr_col,
    const int* __restrict__ rs, float* __restrict__ out, int r0, int r1) {
    int row = r0 + blockIdx.x * 4 + (threadIdx.x >> 6);
    if (row >= r1) return;
    int lane = threadIdx.x & 63;
    int half = lane >> 5;
    int l32  = lane & 31;
    int off  = l32 * 8;   // 8 f16 cols per lane, 32 lanes cover the row

    int s   = rs[row];
    int end = rs[row + 1];

    float acc[8] = {0.f, 0.f, 0.f, 0.f, 0.f, 0.f, 0.f, 0.f};
    if (half == 0) {   // residual h_scaled[row]
        half8 v = *(const half8*)(h16 + (size_t)row * 256 + off);
#pragma unroll
        for (int j = 0; j < 8; j++) acc[j] = (float)v[j];
    }

    int e = s + half;   // half 0 takes even-offset edges, half 1 odd
    for (; e + 2 < end; e += 4) {
        int c0 = csr_col[e];
        int c1 = csr_col[e + 2];
        half8 v0 = *(const half8*)(h16 + (size_t)c0 * 256 + off);
        half8 v1 = *(const half8*)(h16 + (size_t)c1 * 256 + off);
#pragma unroll
        for (int j = 0; j < 8; j++) acc[j] += (float)v0[j] + (float)v1[j];
    }
    for (; e < end; e += 2) {
        int c = csr_col[e];
        half8 v = *(const half8*)(h16 + (size_t)c * 256 + off);
#pragma unroll
        for (int j = 0; j < 8; j++) acc[j] += (float)v[j];
    }

    // cross-half reduction: lane L += lane L+32
#pragma unroll
    for (int j = 0; j < 8; j++) acc[j] += __shfl_down(acc[j], 32);

    if (half == 0) {
        float nrm = rsqrtf(1.0f + (float)(end - s));
        floatx4 o0, o1;
        o0[0] = acc[0] * nrm; o0[1] = acc[1] * nrm; o0[2] = acc[2] * nrm; o0[3] = acc[3] * nrm;
        o1[0] = acc[4] * nrm; o1[1] = acc[5] * nrm; o1[2] = acc[6] * nrm; o1[3] = acc[7] * nrm;
        float* dst = out + (size_t)row * 256 + off;
        __builtin_nontemporal_store(o0, (floatx4*)dst);
        __builtin_nontemporal_store(o1, (floatx4*)(dst + 4));
    }
}

// ---------------------------------------------------------------------------
extern "C" void kernel_launch(void* const* d_in, const int* in_sizes, int n_in,
                              void* d_out, int out_size, void* d_ws, size_t ws_size,
                              hipStream_t stream) {
    const float* x    = (const float*)d_in[0];
    const float* W    = (const float*)d_in[1];
    const float* bias = (const float*)d_in[2];
    const int*   rows = (const int*)d_in[3];
    const int*   cols = (const int*)d_in[4];

    const int D = 256;
    int n = in_sizes[0] / D;    // 100000
    int E = in_sizes[3];        // 3200000
    int nbuck = (n + 255) >> 8; // 391 (<= NB)

    // ---- workspace carve ----
    char* p = (char*)d_ws;
    auto alignup = [](size_t v) { return (v + 255) & ~(size_t)255; };
    _Float16* h16 = (_Float16*)p; p += alignup((size_t)n * D * sizeof(_Float16)); // 51.2 MB
    int*   rs     = (int*)p;    p += alignup((size_t)(n + 1) * sizeof(int));
    int*   csr    = (int*)p;    p += alignup((size_t)E * sizeof(int));            // 12.8 MB
    half8* Bswz   = (half8*)p;  p += alignup((size_t)8192 * sizeof(half8));       // 128 KB
    int*   bcnt   = (int*)p;    p += alignup((size_t)NB * sizeof(int));
    int*   boff   = (int*)p;    p += alignup((size_t)(NB + 1) * sizeof(int));
    int*   bcur   = (int*)p;    p += alignup((size_t)NB * sizeof(int));

    // buf[] (packed 4B per edge, 12.8 MB) overlays the h16 region (51.2 MB);
    // h16 is written by gemm only AFTER csr_finalize has consumed buf.
    uint32_t* buf = (uint32_t*)h16;

    hipMemsetAsync(bcnt, 0, (size_t)nbuck * sizeof(int), stream);

    bucket_count<<<256, THREADS, 0, stream>>>(rows, bcnt, E, nbuck);
    bucket_scan<<<1, THREADS, 0, stream>>>(bcnt, boff, bcur, nbuck, E);

    int b3blocks = (E + B3_EDGES - 1) / B3_EDGES;   // 391
    bucket_scatter<<<b3blocks, THREADS, 0, stream>>>(rows, cols, bcur, buf, E, nbuck);

    csr_finalize<<<nbuck, THREADS, 0, stream>>>(buf, boff, rs, csr, n, E);

    make_bswz<<<32, THREADS, 0, stream>>>(W, Bswz);

    int gblocks = (n + 63) / 64;   // 1563
    gemm_mfma<<<gblocks, THREADS, 0, stream>>>(x, Bswz, bias, rs, h16, n);

    // agg: row-split x2 (keeps -16MB vs feature-split, minimal launch gaps,
    // keeps gemm visible in top-5)
    int half_n = (n + 1) / 2;
    int ab0 = (half_n + 3) / 4;
    int ab1 = ((n - half_n) + 3) / 4;
    agg_rows<<<ab0, THREADS, 0, stream>>>(h16, csr, rs, (float*)d_out, 0, half_n);
    agg_rows<<<ab1, THREADS, 0, stream>>>(h16, csr, rs, (float*)d_out, half_n, n);
}